// Round 4
// baseline (273.593 us; speedup 1.0000x reference)
//
#include <hip/hip_runtime.h>
#include <hip/hip_bf16.h>

typedef __bf16 bf16;
typedef __bf16 bf16x4 __attribute__((ext_vector_type(4)));
typedef __bf16 bf16x8 __attribute__((ext_vector_type(8)));
typedef float f32x4 __attribute__((ext_vector_type(4)));

#define B_ 16
#define N_ 1024
#define F_ 512

__device__ __forceinline__ float rdv(const void* p, size_t i, int f32) {
  return f32 ? ((const float*)p)[i] : (float)((const bf16*)p)[i];
}

// async global->LDS, 16B per lane; LDS dest = wave-uniform base + lane*16
__device__ __forceinline__ void gld16(const bf16* g, bf16* l) {
  __builtin_amdgcn_global_load_lds(
      (const __attribute__((address_space(1))) unsigned int*)g,
      (__attribute__((address_space(3))) unsigned int*)l, 16, 0, 0);
}

// Detect input dtype from W1's raw words (bf16 pair: low half is a small
// weight, exp<=~125; fp32: bits7..14 are mantissa bits, ~49% >= 130).
__global__ void k_detect(const unsigned* __restrict__ w, int* __restrict__ flag) {
  __shared__ int red[256];
  const int t = threadIdx.x;
  int c = 0;
  for (int i = t; i < 4096; i += 256) c += (((w[i] >> 7) & 0xFFu) >= 130u) ? 1 : 0;
  red[t] = c;
  __syncthreads();
  for (int s = 128; s > 0; s >>= 1) {
    if (t < s) red[t] += red[t + s];
    __syncthreads();
  }
  if (t == 0) flag[0] = (red[0] > 100) ? 1 : 0;  // 1 = fp32 inputs
}

// Fused small prep: bias convert (blocks 0..5), W transposes (6..773),
// X -> bf16 copy Xc (774.., 4 elems/thread).
__global__ void k_prep(const void* b1, const void* b2, const void* b3,
                       const void* W1, const void* W2, const void* W3,
                       const void* X, const int* __restrict__ flag,
                       float* __restrict__ bc, bf16* __restrict__ Wt,
                       bf16* __restrict__ xc) {
  __shared__ float tile[32][33];
  const int bid = blockIdx.x;
  const int t = threadIdx.x;
  const int f = flag[0];
  if (bid < 6) {
    const int j = bid * 256 + t;  // 0..1535
    const void* src = (j < 512) ? b1 : (j < 1024 ? b2 : b3);
    bc[j] = rdv(src, (size_t)(j & 511), f);
  } else if (bid < 774) {
    const int bid2 = bid - 6;
    const int z = bid2 >> 8, ti = bid2 & 255;
    const int f0 = (ti & 15) * 32, k0 = (ti >> 4) * 32;
    const int tx = t & 31, ty = t >> 5;
    const void* W = (z == 0) ? W1 : ((z == 1) ? W2 : W3);
    bf16* dst = Wt + (size_t)z * F_ * F_;
#pragma unroll
    for (int s = 0; s < 4; ++s)
      tile[ty + 8 * s][tx] = rdv(W, (size_t)(k0 + ty + 8 * s) * F_ + f0 + tx, f);
    __syncthreads();
#pragma unroll
    for (int s = 0; s < 4; ++s)
      dst[(size_t)(f0 + ty + 8 * s) * F_ + k0 + tx] = (bf16)tile[tx][ty + 8 * s];
  } else {
    const size_t i4 = ((size_t)(bid - 774) * 256 + t) * 4;
    if (f) {
      f32x4 v = *(const f32x4*)((const float*)X + i4);
      bf16 o[4] = {(bf16)v[0], (bf16)v[1], (bf16)v[2], (bf16)v[3]};
      *(ulong1*)&xc[i4] = *(ulong1*)o;  // 8B store
    } else {
      *(ulong1*)&xc[i4] = *(const ulong1*)((const bf16*)X + i4);  // bitcopy
    }
  }
}

// Fused transpose + column-sum partials:
//   adjT[b][i][j] = bf16(adj[b][j][i])
//   csp[j0/64][b][i] = sum_{j in [j0,j0+64)} adj[b][j][i]   (fp32, no atomics)
__global__ void k_tran(const void* adj, const int* __restrict__ flag,
                       bf16* __restrict__ adjT, float* __restrict__ csp) {
  __shared__ float tile[64][65];
  __shared__ float red[4][64];
  const int tx = threadIdx.x, ty = threadIdx.y;  // 16,16
  const int t = ty * 16 + tx;
  const int b = blockIdx.z, i0 = blockIdx.y * 64, j0 = blockIdx.x * 64;
  const size_t sb = (size_t)b * N_ * N_;
  if (flag[0]) {
    const float* src = (const float*)adj + sb;
#pragma unroll
    for (int s = 0; s < 4; ++s) {
      const int jj = ty + 16 * s;
      f32x4 v = *(const f32x4*)&src[(size_t)(j0 + jj) * N_ + i0 + 4 * tx];
#pragma unroll
      for (int u = 0; u < 4; ++u) tile[jj][4 * tx + u] = v[u];
    }
  } else {
    const bf16* src = (const bf16*)adj + sb;
#pragma unroll
    for (int s = 0; s < 4; ++s) {
      const int jj = ty + 16 * s;
      bf16x4 v = *(const bf16x4*)&src[(size_t)(j0 + jj) * N_ + i0 + 4 * tx];
#pragma unroll
      for (int u = 0; u < 4; ++u) tile[jj][4 * tx + u] = (float)v[u];
    }
  }
  __syncthreads();
  // column partial sums over this block's 64 rows (j), per column i
  {
    const int cc = t & 63, g = t >> 6;  // 64 cols x 4 row-groups
    float s = 0.f;
#pragma unroll
    for (int r = 0; r < 16; ++r) s += tile[g * 16 + r][cc];
    red[g][cc] = s;
  }
  // transposed write
  bf16* dst = adjT + sb;
#pragma unroll
  for (int s = 0; s < 4; ++s) {
    const int ii = ty + 16 * s;
    bf16x4 o;
#pragma unroll
    for (int u = 0; u < 4; ++u) o[u] = (bf16)tile[4 * tx + u][ii];
    *(bf16x4*)&dst[(size_t)(i0 + ii) * N_ + j0 + 4 * tx] = o;
  }
  __syncthreads();
  if (t < 64)
    csp[((size_t)(j0 >> 6) * B_ + b) * N_ + i0 + t] =
        red[0][t] + red[1][t] + red[2][t] + red[3][t];
}

// degree scale r = colsum^-1/2 (0 if <=0), colsum = sum of 16 csp slices
__device__ __forceinline__ float rscale(const float* __restrict__ csp, int b, int node) {
  float c = 0.f;
#pragma unroll
  for (int z = 0; z < 16; ++z) c += csp[((size_t)z * B_ + b) * N_ + node];
  return c > 0.f ? rsqrtf(c) : 0.f;
}

// C[M][Nc] = A[M][K] * Bt[Nc][K]^T, with optional column scale (SCALEN:
// v *= r_n), row scale (SCALEM: v = r_m*v), bias, ReLU.
//
// 256x128 tile, BK=64, 8 waves (4M x 2N), per-wave 64x64 output.
// Double-buffered LDS (2 x 48KB), phase-split K-loop (2 phases/K-tile:
// ds_read cluster -> barrier+lgkmcnt(0) -> setprio(1)+16 MFMA -> barrier),
// counted vmcnt(6) at tile top (never 0 mid-loop).  T2 both-sides XOR
// swizzle on staging source + fragment reads (proven in prior 128² kernel).
// Grid: 256 blocks = exactly 16 tiles/batch x 16 batches, 1 block/CU.
// XCD swizzle: id&7 = XCD, 2 batches per XCD, 16 tiles per batch.
template <int BIAS, int RELU, int OUTDYN, int SCALEN, int SCALEM, int GX>
__global__ __launch_bounds__(512, 2)
void k_gemm_bt(const bf16* __restrict__ A, const bf16* __restrict__ Bt,
               const float* __restrict__ bias, void* __restrict__ C,
               const int* __restrict__ flag, const float* __restrict__ csp,
               int Nc, int K, long sA, long sB, long sC) {
  __shared__ __align__(16) char smem[98304];  // 2 x (As 32KB + Bs 16KB)
  const int id = blockIdx.x;
  const int xcd = id & 7, p = id >> 3;   // p in 0..31
  const int bz = xcd * 2 + (p >> 4);     // 2 batches per XCD
  const int tl = p & 15;                 // 16 tiles per batch
  const int bx = tl % GX, by = tl / GX;

  const int tid = threadIdx.x;
  const int wid = tid >> 6, lane = tid & 63;
  const int wm = wid >> 1, wn = wid & 1;  // 4M x 2N wave grid
  const int quad = lane >> 4, l16 = lane & 15;
  const int rl = lane >> 3;               // 0..7 staging row within 8-row issue
  const int cg8 = ((lane & 7) ^ rl) * 8;  // swizzled global col offset (elems)
  const int h = l16 & 7;                  // fragment-read swizzle key

  const bf16* gA = A + (size_t)bz * sA + (size_t)by * 256 * K;
  const bf16* gB = Bt + (size_t)bz * sB + (size_t)bx * 128 * K;

  f32x4 acc[4][4];
#pragma unroll
  for (int i = 0; i < 4; ++i)
#pragma unroll
    for (int j = 0; j < 4; ++j) acc[i][j] = (f32x4){0.f, 0.f, 0.f, 0.f};

  // 6 gld16 per thread per K-tile: A 256 rows (4 issues/wave), B 128 (2)
  auto stage = [&](int d, int k0) {
    bf16* As = (bf16*)(smem + d * 49152);
    bf16* Bs = (bf16*)(smem + d * 49152 + 32768);
#pragma unroll
    for (int i = 0; i < 4; ++i) {
      const int r0 = wid * 32 + i * 8;  // wave-uniform LDS row base
      gld16(gA + (size_t)(r0 + rl) * K + k0 + cg8, &As[r0 * 64]);
    }
#pragma unroll
    for (int i = 0; i < 2; ++i) {
      const int r0 = wid * 16 + i * 8;
      gld16(gB + (size_t)(r0 + rl) * K + k0 + cg8, &Bs[r0 * 64]);
    }
  };

  stage(0, 0);
  const int NT = K >> 6;
  for (int kt = 0; kt < NT; ++kt) {
    const int cur = kt & 1;
    if (kt + 1 < NT) {
      stage(1 - cur, (kt + 1) << 6);  // issue next tile BEFORE counted wait
      asm volatile("s_waitcnt vmcnt(6)\n\ts_barrier" ::: "memory");
    } else {
      asm volatile("s_waitcnt vmcnt(0)\n\ts_barrier" ::: "memory");
    }
    const bf16* As = (const bf16*)(smem + cur * 49152);
    const bf16* Bs = (const bf16*)(smem + cur * 49152 + 32768);
#pragma unroll
    for (int kh = 0; kh < 2; ++kh) {
      bf16x8 af[4], bfv[4];
      const int ko = (((quad + 4 * kh) ^ h) * 8);
#pragma unroll
      for (int tm = 0; tm < 4; ++tm)
        af[tm] = *(const bf16x8*)&As[(wm * 64 + tm * 16 + l16) * 64 + ko];
#pragma unroll
      for (int tn = 0; tn < 4; ++tn)
        bfv[tn] = *(const bf16x8*)&Bs[(wn * 64 + tn * 16 + l16) * 64 + ko];
      // phase boundary: align waves, drain own LDS reads, boost MFMA cluster
      asm volatile("s_barrier\n\ts_waitcnt lgkmcnt(0)" ::: "memory");
      __builtin_amdgcn_s_setprio(1);
#pragma unroll
      for (int tm = 0; tm < 4; ++tm)
#pragma unroll
        for (int tn = 0; tn < 4; ++tn)
          acc[tm][tn] =
              __builtin_amdgcn_mfma_f32_16x16x32_bf16(af[tm], bfv[tn], acc[tm][tn], 0, 0, 0);
      __builtin_amdgcn_s_setprio(0);
      asm volatile("s_barrier" ::: "memory");  // WAR protect before re-stage
    }
  }

  // per-block scale table in LDS (K-loop LDS now free; region is inside
  // buffer-1 As, fully drained after the last phase's trailing barrier)
  float* rsh = (float*)(smem + 73728);  // repack region ends at 73728
  if (SCALEN || SCALEM) {
    const int nsc = SCALEM ? 256 : 128;
    if (tid < nsc) {
      const int node = (SCALEM ? by * 256 : bx * 128) + tid;
      rsh[tid] = rscale(csp, bz, node);
    }
    __syncthreads();
  }

  // C/D layout: col = lane&15, row = quad*4 + reg  [m89/m91]
  const size_t cb = (size_t)bz * sC;
  const int mb_w = by * 256 + wm * 64;
  const int nb_w = bx * 128 + wn * 64;

  if (OUTDYN) {
    const int of32 = flag[0];
#pragma unroll
    for (int tn = 0; tn < 4; ++tn) {
      const int n = nb_w + tn * 16 + l16;
      float bv = BIAS ? bias[n] : 0.f;
      const float cscale = SCALEN ? rsh[wn * 64 + tn * 16 + l16] : 1.f;
#pragma unroll
      for (int tm = 0; tm < 4; ++tm) {
        const int m0 = mb_w + tm * 16 + quad * 4;
#pragma unroll
        for (int r = 0; r < 4; ++r) {
          float v = acc[tm][tn][r];
          if (SCALEM) v *= rsh[wm * 64 + tm * 16 + quad * 4 + r];
          if (SCALEN) v *= cscale;
          v += bv;
          if (RELU) v = v > 0.f ? v : 0.f;
          const size_t idx = cb + (size_t)(m0 + r) * Nc + n;
          if (of32) ((float*)C)[idx] = v;
          else      ((bf16*)C)[idx] = (bf16)v;
        }
      }
    }
  } else {
    // repack through per-wave LDS tile [64][72], then 16B coalesced stores
    bf16* W = (bf16*)smem + wid * (64 * 72);
#pragma unroll
    for (int tn = 0; tn < 4; ++tn) {
      const int n = nb_w + tn * 16 + l16;
      float bv = BIAS ? bias[n] : 0.f;
      const float cscale = SCALEN ? rsh[wn * 64 + tn * 16 + l16] : 1.f;
#pragma unroll
      for (int tm = 0; tm < 4; ++tm) {
#pragma unroll
        for (int r = 0; r < 4; ++r) {
          float v = acc[tm][tn][r];
          if (SCALEM) v *= rsh[wm * 64 + tm * 16 + quad * 4 + r];
          if (SCALEN) v *= cscale;
          v += bv;
          if (RELU) v = v > 0.f ? v : 0.f;
          W[(tm * 16 + quad * 4 + r) * 72 + tn * 16 + l16] = (bf16)v;
        }
      }
    }
    bf16* gC = (bf16*)C + cb;
#pragma unroll
    for (int i = 0; i < 8; ++i) {
      const int row = i * 8 + rl;
      bf16x8 v = *(const bf16x8*)&W[row * 72 + (lane & 7) * 8];
      *(bf16x8*)&gC[(size_t)(mb_w + row) * Nc + nb_w + (lane & 7) * 8] = v;
    }
  }
}

extern "C" void kernel_launch(void* const* d_in, const int* in_sizes, int n_in,
                              void* d_out, int out_size, void* d_ws, size_t ws_size,
                              hipStream_t stream) {
  // ws: csp(1MB) | flag | bc | adjT(32MB) | Wt(1.5MB) | Zt(16MB)  ~50.5MB
  char* ws = (char*)d_ws;
  float* csp  = (float*)ws;                         // 1 MB [16][B][N]
  int*  flag  = (int*)(ws + 1048576);
  float* bc   = (float*)(ws + 1048832);             // 6 KB [3][512]
  bf16* adjT  = (bf16*)(ws + 1056768);              // 32 MB [B][N][N]
  bf16* Wt    = (bf16*)(ws + 1056768 + 33554432);   // 1.5 MB [3][F][F]
  bf16* Zt    = (bf16*)(ws + 1056768 + 33554432 + 3 * F_ * F_ * 2);  // 16 MB
  bf16* Xc = (bf16*)d_out;  // d_out doubles as bf16 activation scratch

  const long sW = 0;
  const long sX = (long)N_ * F_;
  const long sZ = (long)F_ * N_;
  const long sAn = (long)N_ * N_;

  k_detect<<<1, 256, 0, stream>>>((const unsigned*)d_in[2], flag);
  k_prep<<<774 + (B_ * N_ * F_) / 1024, 256, 0, stream>>>(
      d_in[3], d_in[5], d_in[7], d_in[2], d_in[4], d_in[6], d_in[0], flag, bc, Wt, Xc);
  k_tran<<<dim3(N_ / 64, N_ / 64, B_), dim3(16, 16), 0, stream>>>(d_in[1], flag, adjT, csp);

  // GEMM1: Zt = Wt_z @ Xc^T, cols scaled by r_j   (M=F=512 -> by 0..1, Nc=N=1024 -> bx 0..7, K=F, GX=8)
  // GEMM2: X' = r_i * (adjT @ Zt^T) + b, ReLU     (M=N=1024 -> by 0..3, Nc=F=512 -> bx 0..3, K=N, GX=4)
  // layer 1
  k_gemm_bt<0, 0, 0, 1, 0, 8><<<256, 512, 0, stream>>>(Wt,               Xc, nullptr,   Zt, flag, csp, N_, F_, sW, sX, sZ);
  k_gemm_bt<1, 1, 0, 0, 1, 4><<<256, 512, 0, stream>>>(adjT,             Zt, bc,        Xc, flag, csp, F_, N_, sAn, sZ, sX);
  // layer 2
  k_gemm_bt<0, 0, 0, 1, 0, 8><<<256, 512, 0, stream>>>(Wt + F_ * F_,     Xc, nullptr,   Zt, flag, csp, N_, F_, sW, sX, sZ);
  k_gemm_bt<1, 1, 0, 0, 1, 4><<<256, 512, 0, stream>>>(adjT,             Zt, bc + 512,  Xc, flag, csp, F_, N_, sAn, sZ, sX);
  // layer 3
  k_gemm_bt<0, 0, 0, 1, 0, 8><<<256, 512, 0, stream>>>(Wt + 2 * F_ * F_, Xc, nullptr,   Zt, flag, csp, N_, F_, sW, sX, sZ);
  k_gemm_bt<1, 0, 1, 0, 1, 4><<<256, 512, 0, stream>>>(adjT,             Zt, bc + 1024, d_out, flag, csp, F_, N_, sAn, sZ, sX);
}

// Round 5
// 265.588 us; speedup vs baseline: 1.0301x; 1.0301x over previous
//
#include <hip/hip_runtime.h>
#include <hip/hip_bf16.h>

typedef __bf16 bf16;
typedef __bf16 bf16x4 __attribute__((ext_vector_type(4)));
typedef __bf16 bf16x8 __attribute__((ext_vector_type(8)));
typedef float f32x4 __attribute__((ext_vector_type(4)));

#define B_ 16
#define N_ 1024
#define F_ 512

__device__ __forceinline__ float rdv(const void* p, size_t i, int f32) {
  return f32 ? ((const float*)p)[i] : (float)((const bf16*)p)[i];
}

// async global->LDS, 16B per lane; LDS dest = wave-uniform base + lane*16
__device__ __forceinline__ void gld16(const bf16* g, bf16* l) {
  __builtin_amdgcn_global_load_lds(
      (const __attribute__((address_space(1))) unsigned int*)g,
      (__attribute__((address_space(3))) unsigned int*)l, 16, 0, 0);
}

// ---------------------------------------------------------------------------
// Merged prep kernel: every block self-computes the input-dtype flag from
// W1's first 2048 words (bf16 pair: low-half exponent <= ~125; fp32: bits
// 7..14 are exponent, ~49% >= 130), then does its role by blockIdx range:
//   0..5      bias convert -> bc
//   6..773    W transposes -> Wt
//   774..8965 X -> bf16 copy Xc
//   8966..    adj transpose + column-sum partials -> adjT, csp
// Block 0 also publishes flag[0] for the GEMM epilogues (stream-ordered).
// ---------------------------------------------------------------------------
__global__ void k_pre(const void* b1, const void* b2, const void* b3,
                      const void* W1, const void* W2, const void* W3,
                      const void* X, const void* adj,
                      int* __restrict__ flag, float* __restrict__ bc,
                      bf16* __restrict__ Wt, bf16* __restrict__ xc,
                      bf16* __restrict__ adjT, float* __restrict__ csp) {
  __shared__ float tile[64][65];
  __shared__ float red2[4][64];
  __shared__ int fred[4];
  const int bid = blockIdx.x;
  const int t = threadIdx.x;

  // --- self-computed dtype flag (2048 samples of W1) ---
  {
    const unsigned* w = (const unsigned*)W1;
    int c = 0;
#pragma unroll
    for (int i = 0; i < 8; ++i) c += (((w[t + 256 * i] >> 7) & 0xFFu) >= 130u) ? 1 : 0;
#pragma unroll
    for (int o = 32; o > 0; o >>= 1) c += __shfl_down(c, o);
    if ((t & 63) == 0) fred[t >> 6] = c;
  }
  __syncthreads();
  const int f = (fred[0] + fred[1] + fred[2] + fred[3]) > 512;  // 1 = fp32
  if (bid == 0 && t == 0) flag[0] = f;

  if (bid < 6) {
    const int j = bid * 256 + t;  // 0..1535
    const void* src = (j < 512) ? b1 : (j < 1024 ? b2 : b3);
    bc[j] = rdv(src, (size_t)(j & 511), f);
  } else if (bid < 774) {
    // W transpose through a 32x33 sub-tile of the shared tile buffer
    float(*wt32)[65] = tile;  // reuse [32][33-ish] region, stride 65 is fine
    const int bid2 = bid - 6;
    const int z = bid2 >> 8, ti = bid2 & 255;
    const int f0 = (ti & 15) * 32, k0 = (ti >> 4) * 32;
    const int tx = t & 31, ty = t >> 5;
    const void* W = (z == 0) ? W1 : ((z == 1) ? W2 : W3);
    bf16* dst = Wt + (size_t)z * F_ * F_;
#pragma unroll
    for (int s = 0; s < 4; ++s)
      wt32[ty + 8 * s][tx] = rdv(W, (size_t)(k0 + ty + 8 * s) * F_ + f0 + tx, f);
    __syncthreads();
#pragma unroll
    for (int s = 0; s < 4; ++s)
      dst[(size_t)(f0 + ty + 8 * s) * F_ + k0 + tx] = (bf16)wt32[tx][ty + 8 * s];
  } else if (bid < 8966) {
    const size_t i4 = ((size_t)(bid - 774) * 256 + t) * 4;
    if (f) {
      f32x4 v = *(const f32x4*)((const float*)X + i4);
      bf16 o[4] = {(bf16)v[0], (bf16)v[1], (bf16)v[2], (bf16)v[3]};
      *(ulong1*)&xc[i4] = *(ulong1*)o;  // 8B store
    } else {
      *(ulong1*)&xc[i4] = *(const ulong1*)((const bf16*)X + i4);  // bitcopy
    }
  } else {
    // adj transpose + column partial sums (was k_tran)
    const int bid2 = bid - 8966;
    const int tx = t & 15, ty = t >> 4;
    const int b = bid2 >> 8;
    const int i0 = ((bid2 >> 4) & 15) * 64, j0 = (bid2 & 15) * 64;
    const size_t sb = (size_t)b * N_ * N_;
    if (f) {
      const float* src = (const float*)adj + sb;
#pragma unroll
      for (int s = 0; s < 4; ++s) {
        const int jj = ty + 16 * s;
        f32x4 v = *(const f32x4*)&src[(size_t)(j0 + jj) * N_ + i0 + 4 * tx];
#pragma unroll
        for (int u = 0; u < 4; ++u) tile[jj][4 * tx + u] = v[u];
      }
    } else {
      const bf16* src = (const bf16*)adj + sb;
#pragma unroll
      for (int s = 0; s < 4; ++s) {
        const int jj = ty + 16 * s;
        bf16x4 v = *(const bf16x4*)&src[(size_t)(j0 + jj) * N_ + i0 + 4 * tx];
#pragma unroll
        for (int u = 0; u < 4; ++u) tile[jj][4 * tx + u] = (float)v[u];
      }
    }
    __syncthreads();
    // column partial sums over this block's 64 rows (j), per column i
    {
      const int cc = t & 63, g = t >> 6;  // 64 cols x 4 row-groups
      float s = 0.f;
#pragma unroll
      for (int r = 0; r < 16; ++r) s += tile[g * 16 + r][cc];
      red2[g][cc] = s;
    }
    // transposed write
    bf16* dst = adjT + sb;
#pragma unroll
    for (int s = 0; s < 4; ++s) {
      const int ii = ty + 16 * s;
      bf16x4 o;
#pragma unroll
      for (int u = 0; u < 4; ++u) o[u] = (bf16)tile[4 * tx + u][ii];
      *(bf16x4*)&dst[(size_t)(i0 + ii) * N_ + j0 + 4 * tx] = o;
    }
    __syncthreads();
    if (t < 64)
      csp[((size_t)(j0 >> 6) * B_ + b) * N_ + i0 + t] =
          red2[0][t] + red2[1][t] + red2[2][t] + red2[3][t];
  }
}

// degree scale r = colsum^-1/2 (0 if <=0), colsum = sum of 16 csp slices
__device__ __forceinline__ float rscale(const float* __restrict__ csp, int b, int node) {
  float c = 0.f;
#pragma unroll
  for (int z = 0; z < 16; ++z) c += csp[((size_t)z * B_ + b) * N_ + node];
  return c > 0.f ? rsqrtf(c) : 0.f;
}

// C[M][Nc] = A[M][K] * Bt[Nc][K]^T, with optional column scale (SCALEN:
// v *= r_n), row scale (SCALEM: v = r_m*v), bias, ReLU.  128x128 tile, BK=64,
// double-buffered LDS, raw s_barrier pipeline w/ fine-grained vmcnt.
// 1-D grid, XCD swizzle: id%8 = XCD, 2 batches per XCD, 32 tiles per batch.
// (Proven best-measured structure: 2 blocks/CU co-residency.)
template <int BIAS, int RELU, int OUTDYN, int SCALEN, int SCALEM, int GX>
__global__ __launch_bounds__(256)
void k_gemm_bt(const bf16* __restrict__ A, const bf16* __restrict__ Bt,
               const float* __restrict__ bias, void* __restrict__ C,
               const int* __restrict__ flag, const float* __restrict__ csp,
               int Nc, int K, long sA, long sB, long sC) {
  __shared__ __align__(16) char smem[65536];  // 2 x (As 16KB + Bs 16KB)
  const int id = blockIdx.x;
  const int xcd = id & 7, p = id >> 3;
  const int bz = xcd * 2 + (p >> 5);
  const int tl = p & 31;
  const int bx = tl % GX, by = tl / GX;

  const int tid = threadIdx.x;
  const int wid = tid >> 6, lane = tid & 63;
  const int wm = wid >> 1, wn = wid & 1;
  const int quad = lane >> 4, l16 = lane & 15;
  const int rl = lane >> 3;               // 0..7 staging row within 8-row issue
  const int cg8 = ((lane & 7) ^ rl) * 8;  // swizzled global col offset (elems)
  const int h = l16 & 7;                  // fragment-read swizzle key

  const bf16* gA = A + (size_t)bz * sA + (size_t)by * 128 * K;
  const bf16* gB = Bt + (size_t)bz * sB + (size_t)bx * 128 * K;

  f32x4 acc[4][4];
#pragma unroll
  for (int i = 0; i < 4; ++i)
#pragma unroll
    for (int j = 0; j < 4; ++j) acc[i][j] = (f32x4){0.f, 0.f, 0.f, 0.f};

  auto stage = [&](int d, int k0) {
    bf16* As = (bf16*)(smem + d * 32768);
    bf16* Bs = (bf16*)(smem + d * 32768 + 16384);
#pragma unroll
    for (int i = 0; i < 4; ++i) {
      const int r0 = wid * 32 + i * 8;  // wave-uniform LDS row base
      gld16(gA + (size_t)(r0 + rl) * K + k0 + cg8, &As[r0 * 64]);
      gld16(gB + (size_t)(r0 + rl) * K + k0 + cg8, &Bs[r0 * 64]);
    }
  };

  stage(0, 0);
  for (int k0 = 0; k0 < K; k0 += 64) {
    const int cur = (k0 >> 6) & 1;
    if (k0 + 64 < K) {
      stage(1 - cur, k0 + 64);
      asm volatile("s_waitcnt vmcnt(8)\n\ts_barrier" ::: "memory");
    } else {
      asm volatile("s_waitcnt vmcnt(0)\n\ts_barrier" ::: "memory");
    }
    const bf16* As = (const bf16*)(smem + cur * 32768);
    const bf16* Bs = (const bf16*)(smem + cur * 32768 + 16384);
#pragma unroll
    for (int s = 0; s < 2; ++s) {
      bf16x8 af[4], bfv[4];
#pragma unroll
      for (int tm = 0; tm < 4; ++tm)
        af[tm] = *(const bf16x8*)&As[(wm * 64 + tm * 16 + l16) * 64 +
                                     (((quad + 4 * s) ^ h) * 8)];
#pragma unroll
      for (int tn = 0; tn < 4; ++tn)
        bfv[tn] = *(const bf16x8*)&Bs[(wn * 64 + tn * 16 + l16) * 64 +
                                      (((quad + 4 * s) ^ h) * 8)];
#pragma unroll
      for (int tm = 0; tm < 4; ++tm)
#pragma unroll
        for (int tn = 0; tn < 4; ++tn)
          acc[tm][tn] =
              __builtin_amdgcn_mfma_f32_16x16x32_bf16(af[tm], bfv[tn], acc[tm][tn], 0, 0, 0);
    }
    asm volatile("s_barrier" ::: "memory");  // WAR protect (exec barrier only)
  }

  // per-block scale table (128 rows or cols) in LDS (K-loop LDS now free)
  float* rsh = (float*)(smem + 37376);  // repack region ends at 36864
  if (SCALEN || SCALEM) {
    if (tid < 128) {
      const int node = (SCALEM ? by * 128 : bx * 128) + tid;
      rsh[tid] = rscale(csp, bz, node);
    }
    __syncthreads();
  }

  // C/D layout: col = lane&15, row = quad*4 + reg  [m89/m91]
  const size_t cb = (size_t)bz * sC;
  const int mb_w = by * 128 + wm * 64;
  const int nb_w = bx * 128 + wn * 64;

  if (OUTDYN) {
    const int of32 = flag[0];
#pragma unroll
    for (int tn = 0; tn < 4; ++tn) {
      const int n = nb_w + tn * 16 + l16;
      float bv = BIAS ? bias[n] : 0.f;
      const float cscale = SCALEN ? rsh[wn * 64 + tn * 16 + l16] : 1.f;
#pragma unroll
      for (int tm = 0; tm < 4; ++tm) {
        const int m0 = mb_w + tm * 16 + quad * 4;
#pragma unroll
        for (int r = 0; r < 4; ++r) {
          float v = acc[tm][tn][r];
          if (SCALEM) v *= rsh[wm * 64 + tm * 16 + quad * 4 + r];
          if (SCALEN) v *= cscale;
          v += bv;
          if (RELU) v = v > 0.f ? v : 0.f;
          const size_t idx = cb + (size_t)(m0 + r) * Nc + n;
          if (of32) ((float*)C)[idx] = v;
          else      ((bf16*)C)[idx] = (bf16)v;
        }
      }
    }
  } else {
    // repack through per-wave LDS tile [64][72], then 16B coalesced stores
    bf16* W = (bf16*)smem + wid * (64 * 72);
#pragma unroll
    for (int tn = 0; tn < 4; ++tn) {
      const int n = nb_w + tn * 16 + l16;
      float bv = BIAS ? bias[n] : 0.f;
      const float cscale = SCALEN ? rsh[wn * 64 + tn * 16 + l16] : 1.f;
#pragma unroll
      for (int tm = 0; tm < 4; ++tm) {
#pragma unroll
        for (int r = 0; r < 4; ++r) {
          float v = acc[tm][tn][r];
          if (SCALEM) v *= rsh[wm * 64 + tm * 16 + quad * 4 + r];
          if (SCALEN) v *= cscale;
          v += bv;
          if (RELU) v = v > 0.f ? v : 0.f;
          W[(tm * 16 + quad * 4 + r) * 72 + tn * 16 + l16] = (bf16)v;
        }
      }
    }
    bf16* gC = (bf16*)C + cb;
#pragma unroll
    for (int i = 0; i < 8; ++i) {
      const int row = i * 8 + rl;
      bf16x8 v = *(const bf16x8*)&W[row * 72 + (lane & 7) * 8];
      *(bf16x8*)&gC[(size_t)(mb_w + row) * Nc + nb_w + (lane & 7) * 8] = v;
    }
  }
}

extern "C" void kernel_launch(void* const* d_in, const int* in_sizes, int n_in,
                              void* d_out, int out_size, void* d_ws, size_t ws_size,
                              hipStream_t stream) {
  // ws: csp(1MB) | flag | bc | adjT(32MB) | Wt(1.5MB) | Zt(16MB)  ~50.5MB
  char* ws = (char*)d_ws;
  float* csp  = (float*)ws;                         // 1 MB [16][B][N]
  int*  flag  = (int*)(ws + 1048576);
  float* bc   = (float*)(ws + 1048832);             // 6 KB [3][512]
  bf16* adjT  = (bf16*)(ws + 1056768);              // 32 MB [B][N][N]
  bf16* Wt    = (bf16*)(ws + 1056768 + 33554432);   // 1.5 MB [3][F][F]
  bf16* Zt    = (bf16*)(ws + 1056768 + 33554432 + 3 * F_ * F_ * 2);  // 16 MB
  bf16* Xc = (bf16*)d_out;  // d_out doubles as bf16 activation scratch

  const long sW = 0;
  const long sX = (long)N_ * F_;
  const long sZ = (long)F_ * N_;
  const long sAn = (long)N_ * N_;

  // one merged prep dispatch: bias(6) + Wt(768) + Xc(8192) + adjT/csp(4096)
  k_pre<<<6 + 768 + 8192 + 4096, 256, 0, stream>>>(
      d_in[3], d_in[5], d_in[7], d_in[2], d_in[4], d_in[6], d_in[0], d_in[1],
      flag, bc, Wt, Xc, adjT, csp);

  // GEMM1: Zt = Wt_z @ Xc^T, cols scaled by r_j   (M=F, Nc=N, K=F, GX=8)
  // GEMM2: X' = r_i * (adjT @ Zt^T) + b, ReLU     (M=N, Nc=F, K=N, GX=4)
  // layer 1
  k_gemm_bt<0, 0, 0, 1, 0, 8><<<512, 256, 0, stream>>>(Wt,               Xc, nullptr,   Zt, flag, csp, N_, F_, sW, sX, sZ);
  k_gemm_bt<1, 1, 0, 0, 1, 4><<<512, 256, 0, stream>>>(adjT,             Zt, bc,        Xc, flag, csp, F_, N_, sAn, sZ, sX);
  // layer 2
  k_gemm_bt<0, 0, 0, 1, 0, 8><<<512, 256, 0, stream>>>(Wt + F_ * F_,     Xc, nullptr,   Zt, flag, csp, N_, F_, sW, sX, sZ);
  k_gemm_bt<1, 1, 0, 0, 1, 4><<<512, 256, 0, stream>>>(adjT,             Zt, bc + 512,  Xc, flag, csp, F_, N_, sAn, sZ, sX);
  // layer 3
  k_gemm_bt<0, 0, 0, 1, 0, 8><<<512, 256, 0, stream>>>(Wt + 2 * F_ * F_, Xc, nullptr,   Zt, flag, csp, N_, F_, sW, sX, sZ);
  k_gemm_bt<1, 0, 1, 0, 1, 4><<<512, 256, 0, stream>>>(adjT,             Zt, bc + 1024, d_out, flag, csp, F_, N_, sAn, sZ, sX);
}

// Round 6
// 259.302 us; speedup vs baseline: 1.0551x; 1.0242x over previous
//
#include <hip/hip_runtime.h>
#include <hip/hip_bf16.h>

typedef __bf16 bf16;
typedef __bf16 bf16x4 __attribute__((ext_vector_type(4)));
typedef __bf16 bf16x8 __attribute__((ext_vector_type(8)));
typedef float f32x4 __attribute__((ext_vector_type(4)));

#define B_ 16
#define N_ 1024
#define F_ 512

__device__ __forceinline__ float rdv(const void* p, size_t i, int f32) {
  return f32 ? ((const float*)p)[i] : (float)((const bf16*)p)[i];
}

// async global->LDS, 16B per lane; LDS dest = wave-uniform base + lane*16
__device__ __forceinline__ void gld16(const bf16* g, bf16* l) {
  __builtin_amdgcn_global_load_lds(
      (const __attribute__((address_space(1))) unsigned int*)g,
      (__attribute__((address_space(3))) unsigned int*)l, 16, 0, 0);
}

// ---------------------------------------------------------------------------
// Merged prep kernel v2.  Per-WAVE dtype flag via ballot (no LDS / no sync):
// 256 samples of W1's first 1KB; fp32 words have bits7..14 (mantissa) >=130
// ~49% of the time (mean 126/256, sigma 8); bf16-pair words (low half = small
// weight, exponent <= ~125) essentially never.  Threshold 64 = 7.7 sigma.
// Roles by blockIdx:
//   [0,6144)    groups of 3: 1 adj-transpose tile (128j x 64i) + 2 Xc chunks
//   [6144,6912) W transposes -> Wt
//   [6912,6918) bias convert -> bc   (block 6912 publishes flag[0])
// ---------------------------------------------------------------------------
__global__ void k_pre(const void* b1, const void* b2, const void* b3,
                      const void* W1, const void* W2, const void* W3,
                      const void* X, const void* adj,
                      int* __restrict__ flag, float* __restrict__ bc,
                      bf16* __restrict__ Wt, bf16* __restrict__ xc,
                      bf16* __restrict__ adjT, float* __restrict__ csp) {
  __shared__ float tile[128][65];
  __shared__ float red2[4][64];
  const int bid = blockIdx.x;
  const int t = threadIdx.x;

  // --- per-wave dtype flag: 4 words/lane from W1[0..255] (L1-hot) ---
  int f;
  {
    const unsigned* w = (const unsigned*)W1;
    const int l = t & 63;
    int c = 0;
#pragma unroll
    for (int i = 0; i < 4; ++i) {
      unsigned v = w[l + 64 * i];
      c += __popcll(__ballot(((v >> 7) & 0xFFu) >= 130u));
    }
    f = c > 64;  // 1 = fp32 inputs
  }

  if (bid < 6144) {
    const int q = bid / 3, r = bid - 3 * q;
    if (r == 0) {
      // ---- adj transpose tile: 128 j-rows x 64 i-cols ----
      const int b = q >> 7, rem = q & 127;
      const int j0 = (rem >> 4) << 7, i0 = (rem & 15) << 6;
      const size_t sb = (size_t)b * N_ * N_;
      const int tx = t & 15, jr = t >> 4;  // 16 cols-of-4 x 16 rows/pass
      if (f) {
        const float* src = (const float*)adj + sb;
#pragma unroll
        for (int s = 0; s < 8; ++s) {
          const int jj = jr + 16 * s;
          f32x4 v = *(const f32x4*)&src[(size_t)(j0 + jj) * N_ + i0 + 4 * tx];
#pragma unroll
          for (int u = 0; u < 4; ++u) tile[jj][4 * tx + u] = v[u];
        }
      } else {
        const bf16* src = (const bf16*)adj + sb;
#pragma unroll
        for (int s = 0; s < 8; ++s) {
          const int jj = jr + 16 * s;
          bf16x4 v = *(const bf16x4*)&src[(size_t)(j0 + jj) * N_ + i0 + 4 * tx];
#pragma unroll
          for (int u = 0; u < 4; ++u) tile[jj][4 * tx + u] = (float)v[u];
        }
      }
      __syncthreads();
      // column partial sums: 64 cols x 4 groups of 32 rows
      {
        const int cc = t & 63, g = t >> 6;
        float s = 0.f;
#pragma unroll
        for (int rr = 0; rr < 32; ++rr) s += tile[g * 32 + rr][cc];
        red2[g][cc] = s;
      }
      // transposed write: 64 i-rows x 128 j-cols, bf16x8 (16B) stores
      bf16* dst = adjT + sb;
      const int oct = t & 15;
#pragma unroll
      for (int s = 0; s < 4; ++s) {
        const int ii = (t >> 4) + 16 * s;
        bf16x8 o;
#pragma unroll
        for (int u = 0; u < 8; ++u) o[u] = (bf16)tile[8 * oct + u][ii];
        *(bf16x8*)&dst[(size_t)(i0 + ii) * N_ + j0 + 8 * oct] = o;
      }
      __syncthreads();
      if (t < 64)
        csp[((size_t)(j0 >> 7) * B_ + b) * N_ + i0 + t] =
            red2[0][t] + red2[1][t] + red2[2][t] + red2[3][t];
    } else {
      // ---- X -> bf16 copy, 8 elems/thread (16B store) ----
      const int c = 2 * q + (r - 1);  // 0..4095
      const size_t i8 = ((size_t)c * 256 + t) * 8;
      if (f) {
        const float* xf = (const float*)X + i8;
        f32x4 v0 = *(const f32x4*)xf;
        f32x4 v1 = *(const f32x4*)(xf + 4);
        bf16x8 o = {(bf16)v0[0], (bf16)v0[1], (bf16)v0[2], (bf16)v0[3],
                    (bf16)v1[0], (bf16)v1[1], (bf16)v1[2], (bf16)v1[3]};
        *(bf16x8*)&xc[i8] = o;
      } else {
        *(f32x4*)&xc[i8] = *(const f32x4*)((const bf16*)X + i8);  // 16B bitcopy
      }
    }
  } else if (bid < 6912) {
    // ---- W transpose through a 32x32 sub-tile (stride-65 rows) ----
    const int bid2 = bid - 6144;
    const int z = bid2 >> 8, ti = bid2 & 255;
    const int f0 = (ti & 15) * 32, k0 = (ti >> 4) * 32;
    const int tx = t & 31, ty = t >> 5;
    const void* W = (z == 0) ? W1 : ((z == 1) ? W2 : W3);
    bf16* dst = Wt + (size_t)z * F_ * F_;
#pragma unroll
    for (int s = 0; s < 4; ++s)
      tile[ty + 8 * s][tx] = rdv(W, (size_t)(k0 + ty + 8 * s) * F_ + f0 + tx, f);
    __syncthreads();
#pragma unroll
    for (int s = 0; s < 4; ++s)
      dst[(size_t)(f0 + ty + 8 * s) * F_ + k0 + tx] = (bf16)tile[tx][ty + 8 * s];
  } else {
    // ---- bias convert ----
    const int j = (bid - 6912) * 256 + t;  // 0..1535
    const void* src = (j < 512) ? b1 : (j < 1024 ? b2 : b3);
    bc[j] = rdv(src, (size_t)(j & 511), f);
    if (bid == 6912 && t == 0) flag[0] = f;
  }
}

// degree scale r = colsum^-1/2 (0 if <=0), colsum = sum of 8 csp slices
__device__ __forceinline__ float rscale(const float* __restrict__ csp, int b, int node) {
  float c = 0.f;
#pragma unroll
  for (int z = 0; z < 8; ++z) c += csp[((size_t)z * B_ + b) * N_ + node];
  return c > 0.f ? rsqrtf(c) : 0.f;
}

// C[M][Nc] = A[M][K] * Bt[Nc][K]^T, with optional column scale (SCALEN:
// v *= r_n), row scale (SCALEM: v = r_m*v), bias, ReLU.  128x128 tile, BK=64,
// double-buffered LDS, raw s_barrier pipeline w/ fine-grained vmcnt.
// 1-D grid, XCD swizzle: id%8 = XCD, 2 batches per XCD, 32 tiles per batch.
// (Proven best-measured structure: 2 blocks/CU co-residency.)
template <int BIAS, int RELU, int OUTDYN, int SCALEN, int SCALEM, int GX>
__global__ __launch_bounds__(256)
void k_gemm_bt(const bf16* __restrict__ A, const bf16* __restrict__ Bt,
               const float* __restrict__ bias, void* __restrict__ C,
               const int* __restrict__ flag, const float* __restrict__ csp,
               int Nc, int K, long sA, long sB, long sC) {
  __shared__ __align__(16) char smem[65536];  // 2 x (As 16KB + Bs 16KB)
  const int id = blockIdx.x;
  const int xcd = id & 7, p = id >> 3;
  const int bz = xcd * 2 + (p >> 5);
  const int tl = p & 31;
  const int bx = tl % GX, by = tl / GX;

  const int tid = threadIdx.x;
  const int wid = tid >> 6, lane = tid & 63;
  const int wm = wid >> 1, wn = wid & 1;
  const int quad = lane >> 4, l16 = lane & 15;
  const int rl = lane >> 3;               // 0..7 staging row within 8-row issue
  const int cg8 = ((lane & 7) ^ rl) * 8;  // swizzled global col offset (elems)
  const int h = l16 & 7;                  // fragment-read swizzle key

  const bf16* gA = A + (size_t)bz * sA + (size_t)by * 128 * K;
  const bf16* gB = Bt + (size_t)bz * sB + (size_t)bx * 128 * K;

  f32x4 acc[4][4];
#pragma unroll
  for (int i = 0; i < 4; ++i)
#pragma unroll
    for (int j = 0; j < 4; ++j) acc[i][j] = (f32x4){0.f, 0.f, 0.f, 0.f};

  auto stage = [&](int d, int k0) {
    bf16* As = (bf16*)(smem + d * 32768);
    bf16* Bs = (bf16*)(smem + d * 32768 + 16384);
#pragma unroll
    for (int i = 0; i < 4; ++i) {
      const int r0 = wid * 32 + i * 8;  // wave-uniform LDS row base
      gld16(gA + (size_t)(r0 + rl) * K + k0 + cg8, &As[r0 * 64]);
      gld16(gB + (size_t)(r0 + rl) * K + k0 + cg8, &Bs[r0 * 64]);
    }
  };

  stage(0, 0);
  for (int k0 = 0; k0 < K; k0 += 64) {
    const int cur = (k0 >> 6) & 1;
    if (k0 + 64 < K) {
      stage(1 - cur, k0 + 64);
      asm volatile("s_waitcnt vmcnt(8)\n\ts_barrier" ::: "memory");
    } else {
      asm volatile("s_waitcnt vmcnt(0)\n\ts_barrier" ::: "memory");
    }
    const bf16* As = (const bf16*)(smem + cur * 32768);
    const bf16* Bs = (const bf16*)(smem + cur * 32768 + 16384);
#pragma unroll
    for (int s = 0; s < 2; ++s) {
      bf16x8 af[4], bfv[4];
#pragma unroll
      for (int tm = 0; tm < 4; ++tm)
        af[tm] = *(const bf16x8*)&As[(wm * 64 + tm * 16 + l16) * 64 +
                                     (((quad + 4 * s) ^ h) * 8)];
#pragma unroll
      for (int tn = 0; tn < 4; ++tn)
        bfv[tn] = *(const bf16x8*)&Bs[(wn * 64 + tn * 16 + l16) * 64 +
                                      (((quad + 4 * s) ^ h) * 8)];
#pragma unroll
      for (int tm = 0; tm < 4; ++tm)
#pragma unroll
        for (int tn = 0; tn < 4; ++tn)
          acc[tm][tn] =
              __builtin_amdgcn_mfma_f32_16x16x32_bf16(af[tm], bfv[tn], acc[tm][tn], 0, 0, 0);
    }
    asm volatile("s_barrier" ::: "memory");  // WAR protect (exec barrier only)
  }

  // per-block scale table (128 rows or cols) in LDS (K-loop LDS now free)
  float* rsh = (float*)(smem + 37376);  // repack region ends at 36864
  if (SCALEN || SCALEM) {
    if (tid < 128) {
      const int node = (SCALEM ? by * 128 : bx * 128) + tid;
      rsh[tid] = rscale(csp, bz, node);
    }
    __syncthreads();
  }

  // C/D layout: col = lane&15, row = quad*4 + reg  [m89/m91]
  const size_t cb = (size_t)bz * sC;
  const int mb_w = by * 128 + wm * 64;
  const int nb_w = bx * 128 + wn * 64;

  if (OUTDYN) {
    const int of32 = flag[0];
#pragma unroll
    for (int tn = 0; tn < 4; ++tn) {
      const int n = nb_w + tn * 16 + l16;
      float bv = BIAS ? bias[n] : 0.f;
      const float cscale = SCALEN ? rsh[wn * 64 + tn * 16 + l16] : 1.f;
#pragma unroll
      for (int tm = 0; tm < 4; ++tm) {
        const int m0 = mb_w + tm * 16 + quad * 4;
#pragma unroll
        for (int r = 0; r < 4; ++r) {
          float v = acc[tm][tn][r];
          if (SCALEM) v *= rsh[wm * 64 + tm * 16 + quad * 4 + r];
          if (SCALEN) v *= cscale;
          v += bv;
          if (RELU) v = v > 0.f ? v : 0.f;
          const size_t idx = cb + (size_t)(m0 + r) * Nc + n;
          if (of32) ((float*)C)[idx] = v;
          else      ((bf16*)C)[idx] = (bf16)v;
        }
      }
    }
  } else {
    // repack through per-wave LDS tile [64][72], then 16B coalesced stores
    bf16* W = (bf16*)smem + wid * (64 * 72);
#pragma unroll
    for (int tn = 0; tn < 4; ++tn) {
      const int n = nb_w + tn * 16 + l16;
      float bv = BIAS ? bias[n] : 0.f;
      const float cscale = SCALEN ? rsh[wn * 64 + tn * 16 + l16] : 1.f;
#pragma unroll
      for (int tm = 0; tm < 4; ++tm) {
#pragma unroll
        for (int r = 0; r < 4; ++r) {
          float v = acc[tm][tn][r];
          if (SCALEM) v *= rsh[wm * 64 + tm * 16 + quad * 4 + r];
          if (SCALEN) v *= cscale;
          v += bv;
          if (RELU) v = v > 0.f ? v : 0.f;
          W[(tm * 16 + quad * 4 + r) * 72 + tn * 16 + l16] = (bf16)v;
        }
      }
    }
    bf16* gC = (bf16*)C + cb;
#pragma unroll
    for (int i = 0; i < 8; ++i) {
      const int row = i * 8 + rl;
      bf16x8 v = *(const bf16x8*)&W[row * 72 + (lane & 7) * 8];
      *(bf16x8*)&gC[(size_t)(mb_w + row) * Nc + nb_w + (lane & 7) * 8] = v;
    }
  }
}

extern "C" void kernel_launch(void* const* d_in, const int* in_sizes, int n_in,
                              void* d_out, int out_size, void* d_ws, size_t ws_size,
                              hipStream_t stream) {
  // ws: csp(512KB used of 1MB) | flag | bc | adjT(32MB) | Wt(1.5MB) | Zt(16MB)
  char* ws = (char*)d_ws;
  float* csp  = (float*)ws;                         // [8][B][N] fp32
  int*  flag  = (int*)(ws + 1048576);
  float* bc   = (float*)(ws + 1048832);             // 6 KB [3][512]
  bf16* adjT  = (bf16*)(ws + 1056768);              // 32 MB [B][N][N]
  bf16* Wt    = (bf16*)(ws + 1056768 + 33554432);   // 1.5 MB [3][F][F]
  bf16* Zt    = (bf16*)(ws + 1056768 + 33554432 + 3 * F_ * F_ * 2);  // 16 MB
  bf16* Xc = (bf16*)d_out;  // d_out doubles as bf16 activation scratch

  const long sW = 0;
  const long sX = (long)N_ * F_;
  const long sZ = (long)F_ * N_;
  const long sAn = (long)N_ * N_;

  // one merged prep dispatch: {tran+2xXc}x2048 + Wt(768) + bias(6)
  k_pre<<<6144 + 768 + 6, 256, 0, stream>>>(
      d_in[3], d_in[5], d_in[7], d_in[2], d_in[4], d_in[6], d_in[0], d_in[1],
      flag, bc, Wt, Xc, adjT, csp);

  // GEMM1: Zt = Wt_z @ Xc^T, cols scaled by r_j   (M=F, Nc=N, K=F, GX=8)
  // GEMM2: X' = r_i * (adjT @ Zt^T) + b, ReLU     (M=N, Nc=F, K=N, GX=4)
  // layer 1
  k_gemm_bt<0, 0, 0, 1, 0, 8><<<512, 256, 0, stream>>>(Wt,               Xc, nullptr,   Zt, flag, csp, N_, F_, sW, sX, sZ);
  k_gemm_bt<1, 1, 0, 0, 1, 4><<<512, 256, 0, stream>>>(adjT,             Zt, bc,        Xc, flag, csp, F_, N_, sAn, sZ, sX);
  // layer 2
  k_gemm_bt<0, 0, 0, 1, 0, 8><<<512, 256, 0, stream>>>(Wt + F_ * F_,     Xc, nullptr,   Zt, flag, csp, N_, F_, sW, sX, sZ);
  k_gemm_bt<1, 1, 0, 0, 1, 4><<<512, 256, 0, stream>>>(adjT,             Zt, bc + 512,  Xc, flag, csp, F_, N_, sAn, sZ, sX);
  // layer 3
  k_gemm_bt<0, 0, 0, 1, 0, 8><<<512, 256, 0, stream>>>(Wt + 2 * F_ * F_, Xc, nullptr,   Zt, flag, csp, N_, F_, sW, sX, sZ);
  k_gemm_bt<1, 0, 1, 0, 1, 4><<<512, 256, 0, stream>>>(adjT,             Zt, bc + 1024, d_out, flag, csp, F_, N_, sAn, sZ, sX);
}

// Round 7
// 253.734 us; speedup vs baseline: 1.0783x; 1.0219x over previous
//
#include <hip/hip_runtime.h>
#include <hip/hip_bf16.h>

typedef __bf16 bf16;
typedef __bf16 bf16x4 __attribute__((ext_vector_type(4)));
typedef __bf16 bf16x8 __attribute__((ext_vector_type(8)));
typedef float f32x4 __attribute__((ext_vector_type(4)));

#define B_ 16
#define N_ 1024
#define F_ 512

__device__ __forceinline__ float rdv(const void* p, size_t i, int f32) {
  return f32 ? ((const float*)p)[i] : (float)((const bf16*)p)[i];
}

// async global->LDS, 16B per lane; LDS dest = wave-uniform base + lane*16
__device__ __forceinline__ void gld16(const bf16* g, bf16* l) {
  __builtin_amdgcn_global_load_lds(
      (const __attribute__((address_space(1))) unsigned int*)g,
      (__attribute__((address_space(3))) unsigned int*)l, 16, 0, 0);
}

// ---------------------------------------------------------------------------
// Merged prep kernel v3.  Per-WAVE dtype flag via ballot (no LDS / no sync).
// Role fusion for latency hiding: blocks [0,2048) EACH do {2 Xc chunks + 1
// adj-transpose tile}.  Order of issue: Xc loads FIRST, adj-tile loads second
// (vmcnt retires in-order, so Xc convert+store only waits for its own loads
// and executes while the adj tile is in flight), then LDS transpose+colsum.
//   [0,2048)     fused: Xc chunks 2q,2q+1  +  adj tile (128j x 64i) -> adjT,csp
//   [2048,2816)  W transposes -> Wt
//   [2816,2822)  bias convert -> bc   (block 2816 publishes flag[0])
// ---------------------------------------------------------------------------
__global__ __launch_bounds__(256)
void k_pre(const void* b1, const void* b2, const void* b3,
           const void* W1, const void* W2, const void* W3,
           const void* X, const void* adj,
           int* __restrict__ flag, float* __restrict__ bc,
           bf16* __restrict__ Wt, bf16* __restrict__ xc,
           bf16* __restrict__ adjT, float* __restrict__ csp) {
  __shared__ float tile[128][65];
  __shared__ float red2[4][64];
  const int bid = blockIdx.x;
  const int t = threadIdx.x;

  // --- per-wave dtype flag: 4 words/lane from W1[0..255] (L1-hot) ---
  int f;
  {
    const unsigned* w = (const unsigned*)W1;
    const int l = t & 63;
    int c = 0;
#pragma unroll
    for (int i = 0; i < 4; ++i) {
      unsigned v = w[l + 64 * i];
      c += __popcll(__ballot(((v >> 7) & 0xFFu) >= 130u));
    }
    f = c > 64;  // 1 = fp32 inputs
  }

  if (bid < 2048) {
    const int q = bid;
    const int b = q >> 7, rem = q & 127;
    const int j0 = (rem >> 4) << 7, i0 = (rem & 15) << 6;
    const size_t sb = (size_t)b * N_ * N_;
    const int tx = t & 15, jr = t >> 4;  // 16 cols-of-4 x 16 rows/pass

    if (f) {
      // ---- issue Xc loads first (fp32 path) ----
      const size_t i8a = ((size_t)(2 * q) * 256 + t) * 8;
      const size_t i8b = ((size_t)(2 * q + 1) * 256 + t) * 8;
      const float* xa = (const float*)X + i8a;
      const float* xb = (const float*)X + i8b;
      f32x4 xv0 = *(const f32x4*)xa;
      f32x4 xv1 = *(const f32x4*)(xa + 4);
      f32x4 xv2 = *(const f32x4*)xb;
      f32x4 xv3 = *(const f32x4*)(xb + 4);
      // ---- issue adj tile loads (8 x f32x4) ----
      const float* src = (const float*)adj + sb;
      f32x4 av[8];
#pragma unroll
      for (int s = 0; s < 8; ++s)
        av[s] = *(const f32x4*)&src[(size_t)(j0 + jr + 16 * s) * N_ + i0 + 4 * tx];
      // ---- Xc convert+store (overlaps adj latency) ----
      {
        bf16x8 o0 = {(bf16)xv0[0], (bf16)xv0[1], (bf16)xv0[2], (bf16)xv0[3],
                     (bf16)xv1[0], (bf16)xv1[1], (bf16)xv1[2], (bf16)xv1[3]};
        bf16x8 o1 = {(bf16)xv2[0], (bf16)xv2[1], (bf16)xv2[2], (bf16)xv2[3],
                     (bf16)xv3[0], (bf16)xv3[1], (bf16)xv3[2], (bf16)xv3[3]};
        *(bf16x8*)&xc[i8a] = o0;
        *(bf16x8*)&xc[i8b] = o1;
      }
      // ---- LDS fill ----
#pragma unroll
      for (int s = 0; s < 8; ++s) *(f32x4*)&tile[jr + 16 * s][4 * tx] = av[s];
    } else {
      // ---- bf16 path: Xc is a bitcopy; adj loads are bf16x4 ----
      const size_t i8a = ((size_t)(2 * q) * 256 + t) * 8;
      const size_t i8b = ((size_t)(2 * q + 1) * 256 + t) * 8;
      f32x4 xv0 = *(const f32x4*)((const bf16*)X + i8a);
      f32x4 xv1 = *(const f32x4*)((const bf16*)X + i8b);
      const bf16* src = (const bf16*)adj + sb;
      bf16x4 av[8];
#pragma unroll
      for (int s = 0; s < 8; ++s)
        av[s] = *(const bf16x4*)&src[(size_t)(j0 + jr + 16 * s) * N_ + i0 + 4 * tx];
      *(f32x4*)&xc[i8a] = xv0;
      *(f32x4*)&xc[i8b] = xv1;
#pragma unroll
      for (int s = 0; s < 8; ++s) {
        float w0 = (float)av[s][0], w1 = (float)av[s][1];
        float w2 = (float)av[s][2], w3 = (float)av[s][3];
        *(f32x4*)&tile[jr + 16 * s][4 * tx] = (f32x4){w0, w1, w2, w3};
      }
    }
    __syncthreads();
    // column partial sums: 64 cols x 4 groups of 32 rows
    {
      const int cc = t & 63, g = t >> 6;
      float s = 0.f;
#pragma unroll
      for (int rr = 0; rr < 32; ++rr) s += tile[g * 32 + rr][cc];
      red2[g][cc] = s;
    }
    // transposed write: 64 i-rows x 128 j-cols, bf16x8 (16B) stores
    bf16* dst = adjT + sb;
    const int oct = t & 15;
#pragma unroll
    for (int s = 0; s < 4; ++s) {
      const int ii = (t >> 4) + 16 * s;
      bf16x8 o;
#pragma unroll
      for (int u = 0; u < 8; ++u) o[u] = (bf16)tile[8 * oct + u][ii];
      *(bf16x8*)&dst[(size_t)(i0 + ii) * N_ + j0 + 8 * oct] = o;
    }
    __syncthreads();
    if (t < 64)
      csp[((size_t)(j0 >> 7) * B_ + b) * N_ + i0 + t] =
          red2[0][t] + red2[1][t] + red2[2][t] + red2[3][t];
  } else if (bid < 2816) {
    // ---- W transpose through a 32x32 sub-tile (stride-65 rows) ----
    const int bid2 = bid - 2048;
    const int z = bid2 >> 8, ti = bid2 & 255;
    const int f0 = (ti & 15) * 32, k0 = (ti >> 4) * 32;
    const int tx = t & 31, ty = t >> 5;
    const void* W = (z == 0) ? W1 : ((z == 1) ? W2 : W3);
    bf16* dst = Wt + (size_t)z * F_ * F_;
#pragma unroll
    for (int s = 0; s < 4; ++s)
      tile[ty + 8 * s][tx] = rdv(W, (size_t)(k0 + ty + 8 * s) * F_ + f0 + tx, f);
    __syncthreads();
#pragma unroll
    for (int s = 0; s < 4; ++s)
      dst[(size_t)(f0 + ty + 8 * s) * F_ + k0 + tx] = (bf16)tile[tx][ty + 8 * s];
  } else {
    // ---- bias convert ----
    const int j = (bid - 2816) * 256 + t;  // 0..1535
    const void* src = (j < 512) ? b1 : (j < 1024 ? b2 : b3);
    bc[j] = rdv(src, (size_t)(j & 511), f);
    if (bid == 2816 && t == 0) flag[0] = f;
  }
}

// degree scale r = colsum^-1/2 (0 if <=0), colsum = sum of 8 csp slices
__device__ __forceinline__ float rscale(const float* __restrict__ csp, int b, int node) {
  float c = 0.f;
#pragma unroll
  for (int z = 0; z < 8; ++z) c += csp[((size_t)z * B_ + b) * N_ + node];
  return c > 0.f ? rsqrtf(c) : 0.f;
}

// C[M][Nc] = A[M][K] * Bt[Nc][K]^T, with optional column scale (SCALEN:
// v *= r_n), row scale (SCALEM: v = r_m*v), bias, ReLU.  128x128 tile, BK=64,
// double-buffered LDS, raw s_barrier pipeline w/ fine-grained vmcnt.
// 1-D grid, XCD swizzle: id%8 = XCD, 2 batches per XCD, 32 tiles per batch.
// (Proven best-measured structure: 2 blocks/CU co-residency.)
template <int BIAS, int RELU, int OUTDYN, int SCALEN, int SCALEM, int GX>
__global__ __launch_bounds__(256)
void k_gemm_bt(const bf16* __restrict__ A, const bf16* __restrict__ Bt,
               const float* __restrict__ bias, void* __restrict__ C,
               const int* __restrict__ flag, const float* __restrict__ csp,
               int Nc, int K, long sA, long sB, long sC) {
  __shared__ __align__(16) char smem[65536];  // 2 x (As 16KB + Bs 16KB)
  const int id = blockIdx.x;
  const int xcd = id & 7, p = id >> 3;
  const int bz = xcd * 2 + (p >> 5);
  const int tl = p & 31;
  const int bx = tl % GX, by = tl / GX;

  const int tid = threadIdx.x;
  const int wid = tid >> 6, lane = tid & 63;
  const int wm = wid >> 1, wn = wid & 1;
  const int quad = lane >> 4, l16 = lane & 15;
  const int rl = lane >> 3;               // 0..7 staging row within 8-row issue
  const int cg8 = ((lane & 7) ^ rl) * 8;  // swizzled global col offset (elems)
  const int h = l16 & 7;                  // fragment-read swizzle key

  const bf16* gA = A + (size_t)bz * sA + (size_t)by * 128 * K;
  const bf16* gB = Bt + (size_t)bz * sB + (size_t)bx * 128 * K;

  f32x4 acc[4][4];
#pragma unroll
  for (int i = 0; i < 4; ++i)
#pragma unroll
    for (int j = 0; j < 4; ++j) acc[i][j] = (f32x4){0.f, 0.f, 0.f, 0.f};

  auto stage = [&](int d, int k0) {
    bf16* As = (bf16*)(smem + d * 32768);
    bf16* Bs = (bf16*)(smem + d * 32768 + 16384);
#pragma unroll
    for (int i = 0; i < 4; ++i) {
      const int r0 = wid * 32 + i * 8;  // wave-uniform LDS row base
      gld16(gA + (size_t)(r0 + rl) * K + k0 + cg8, &As[r0 * 64]);
      gld16(gB + (size_t)(r0 + rl) * K + k0 + cg8, &Bs[r0 * 64]);
    }
  };

  stage(0, 0);
  for (int k0 = 0; k0 < K; k0 += 64) {
    const int cur = (k0 >> 6) & 1;
    if (k0 + 64 < K) {
      stage(1 - cur, k0 + 64);
      asm volatile("s_waitcnt vmcnt(8)\n\ts_barrier" ::: "memory");
    } else {
      asm volatile("s_waitcnt vmcnt(0)\n\ts_barrier" ::: "memory");
    }
    const bf16* As = (const bf16*)(smem + cur * 32768);
    const bf16* Bs = (const bf16*)(smem + cur * 32768 + 16384);
#pragma unroll
    for (int s = 0; s < 2; ++s) {
      bf16x8 af[4], bfv[4];
#pragma unroll
      for (int tm = 0; tm < 4; ++tm)
        af[tm] = *(const bf16x8*)&As[(wm * 64 + tm * 16 + l16) * 64 +
                                     (((quad + 4 * s) ^ h) * 8)];
#pragma unroll
      for (int tn = 0; tn < 4; ++tn)
        bfv[tn] = *(const bf16x8*)&Bs[(wn * 64 + tn * 16 + l16) * 64 +
                                      (((quad + 4 * s) ^ h) * 8)];
#pragma unroll
      for (int tm = 0; tm < 4; ++tm)
#pragma unroll
        for (int tn = 0; tn < 4; ++tn)
          acc[tm][tn] =
              __builtin_amdgcn_mfma_f32_16x16x32_bf16(af[tm], bfv[tn], acc[tm][tn], 0, 0, 0);
    }
    asm volatile("s_barrier" ::: "memory");  // WAR protect (exec barrier only)
  }

  // per-block scale table (128 rows or cols) in LDS (K-loop LDS now free)
  float* rsh = (float*)(smem + 37376);  // repack region ends at 36864
  if (SCALEN || SCALEM) {
    if (tid < 128) {
      const int node = (SCALEM ? by * 128 : bx * 128) + tid;
      rsh[tid] = rscale(csp, bz, node);
    }
    __syncthreads();
  }

  // C/D layout: col = lane&15, row = quad*4 + reg  [m89/m91]
  const size_t cb = (size_t)bz * sC;
  const int mb_w = by * 128 + wm * 64;
  const int nb_w = bx * 128 + wn * 64;

  if (OUTDYN) {
    const int of32 = flag[0];
#pragma unroll
    for (int tn = 0; tn < 4; ++tn) {
      const int n = nb_w + tn * 16 + l16;
      float bv = BIAS ? bias[n] : 0.f;
      const float cscale = SCALEN ? rsh[wn * 64 + tn * 16 + l16] : 1.f;
#pragma unroll
      for (int tm = 0; tm < 4; ++tm) {
        const int m0 = mb_w + tm * 16 + quad * 4;
#pragma unroll
        for (int r = 0; r < 4; ++r) {
          float v = acc[tm][tn][r];
          if (SCALEM) v *= rsh[wm * 64 + tm * 16 + quad * 4 + r];
          if (SCALEN) v *= cscale;
          v += bv;
          if (RELU) v = v > 0.f ? v : 0.f;
          const size_t idx = cb + (size_t)(m0 + r) * Nc + n;
          if (of32) ((float*)C)[idx] = v;
          else      ((bf16*)C)[idx] = (bf16)v;
        }
      }
    }
  } else {
    // repack through per-wave LDS tile [64][72], then 16B coalesced stores
    bf16* W = (bf16*)smem + wid * (64 * 72);
#pragma unroll
    for (int tn = 0; tn < 4; ++tn) {
      const int n = nb_w + tn * 16 + l16;
      float bv = BIAS ? bias[n] : 0.f;
      const float cscale = SCALEN ? rsh[wn * 64 + tn * 16 + l16] : 1.f;
#pragma unroll
      for (int tm = 0; tm < 4; ++tm) {
#pragma unroll
        for (int r = 0; r < 4; ++r) {
          float v = acc[tm][tn][r];
          if (SCALEM) v *= rsh[wm * 64 + tm * 16 + quad * 4 + r];
          if (SCALEN) v *= cscale;
          v += bv;
          if (RELU) v = v > 0.f ? v : 0.f;
          W[(tm * 16 + quad * 4 + r) * 72 + tn * 16 + l16] = (bf16)v;
        }
      }
    }
    bf16* gC = (bf16*)C + cb;
#pragma unroll
    for (int i = 0; i < 8; ++i) {
      const int row = i * 8 + rl;
      bf16x8 v = *(const bf16x8*)&W[row * 72 + (lane & 7) * 8];
      *(bf16x8*)&gC[(size_t)(mb_w + row) * Nc + nb_w + (lane & 7) * 8] = v;
    }
  }
}

extern "C" void kernel_launch(void* const* d_in, const int* in_sizes, int n_in,
                              void* d_out, int out_size, void* d_ws, size_t ws_size,
                              hipStream_t stream) {
  // ws: csp(512KB used of 1MB) | flag | bc | adjT(32MB) | Wt(1.5MB) | Zt(16MB)
  char* ws = (char*)d_ws;
  float* csp  = (float*)ws;                         // [8][B][N] fp32
  int*  flag  = (int*)(ws + 1048576);
  float* bc   = (float*)(ws + 1048832);             // 6 KB [3][512]
  bf16* adjT  = (bf16*)(ws + 1056768);              // 32 MB [B][N][N]
  bf16* Wt    = (bf16*)(ws + 1056768 + 33554432);   // 1.5 MB [3][F][F]
  bf16* Zt    = (bf16*)(ws + 1056768 + 33554432 + 3 * F_ * F_ * 2);  // 16 MB
  bf16* Xc = (bf16*)d_out;  // d_out doubles as bf16 activation scratch

  const long sW = 0;
  const long sX = (long)N_ * F_;
  const long sZ = (long)F_ * N_;
  const long sAn = (long)N_ * N_;

  // one merged prep dispatch: fused {2xXc + tran} x2048 + Wt(768) + bias(6)
  k_pre<<<2048 + 768 + 6, 256, 0, stream>>>(
      d_in[3], d_in[5], d_in[7], d_in[2], d_in[4], d_in[6], d_in[0], d_in[1],
      flag, bc, Wt, Xc, adjT, csp);

  // GEMM1: Zt = Wt_z @ Xc^T, cols scaled by r_j   (M=F, Nc=N, K=F, GX=8)
  // GEMM2: X' = r_i * (adjT @ Zt^T) + b, ReLU     (M=N, Nc=F, K=N, GX=4)
  // layer 1
  k_gemm_bt<0, 0, 0, 1, 0, 8><<<512, 256, 0, stream>>>(Wt,               Xc, nullptr,   Zt, flag, csp, N_, F_, sW, sX, sZ);
  k_gemm_bt<1, 1, 0, 0, 1, 4><<<512, 256, 0, stream>>>(adjT,             Zt, bc,        Xc, flag, csp, F_, N_, sAn, sZ, sX);
  // layer 2
  k_gemm_bt<0, 0, 0, 1, 0, 8><<<512, 256, 0, stream>>>(Wt + F_ * F_,     Xc, nullptr,   Zt, flag, csp, N_, F_, sW, sX, sZ);
  k_gemm_bt<1, 1, 0, 0, 1, 4><<<512, 256, 0, stream>>>(adjT,             Zt, bc + 512,  Xc, flag, csp, F_, N_, sAn, sZ, sX);
  // layer 3
  k_gemm_bt<0, 0, 0, 1, 0, 8><<<512, 256, 0, stream>>>(Wt + 2 * F_ * F_, Xc, nullptr,   Zt, flag, csp, N_, F_, sW, sX, sZ);
  k_gemm_bt<1, 0, 1, 0, 1, 4><<<512, 256, 0, stream>>>(adjT,             Zt, bc + 1024, d_out, flag, csp, F_, N_, sAn, sZ, sX);
}